// Round 5
// baseline (673.411 us; speedup 1.0000x reference)
//
#include <hip/hip_runtime.h>
#include <hip/hip_bf16.h>
#include <cstdint>
#include <cstddef>

#define NTHREADS 1024
#define BB 16
#define NN 256
#define EPAD 33792        // 33280 chart + 512 guard (guard stays zero)
#define PSTR 260          // Part row stride in floats (multiple of 4)

typedef unsigned char u8;

// Mask arrays may arrive as bool (1 byte), int32, or float32. Detect on
// device: maskspan[0,0,1] == 1 always (lens >= 128). Byte storage -> byte1
// == 1; 4-byte storage -> byte1 == 0 (nonzero int/float bit pattern test).
__device__ __forceinline__ bool mask_val(const void* p, size_t idx, bool isbyte) {
  return isbyte ? (((const u8*)p)[idx] != 0) : (((const int*)p)[idx] != 0);
}

__device__ __forceinline__ float score_val(float2 v, const void* sind, size_t cell,
                                           int run, bool isbyte) {
  if (run == 0) return mask_val(sind, cell, isbyte) ? v.y : v.x;  // ob
  float m = fmaxf(v.x, v.y);                                      // allp
  return m + __logf(1.f + __expf(-fabsf(v.x - v.y)));
}

// prefix of padded diagonal sizes: Fpad(M) = sum_{j=1..M} ((j+3)&~3)
__device__ __forceinline__ int Fpad(int M) {
  int f = M >> 2, r = M & 3;
  return 8*f*f + 8*f + 4*r*(f+1);
}

extern "C" __global__ void __launch_bounds__(NTHREADS, 1)
cyk_kernel(const float2* __restrict__ slog, const void* __restrict__ sind,
           const void* __restrict__ mspan, float* __restrict__ wsv) {
  // Exp-space chart, diagonal-major, each diagonal 16B-aligned.
  // alpha(d,c) = log(E[off4[d]+c]) + Mar[d]; Mar[d] = true max alpha of diag
  // d-1 (delayed renorm). All 16 waves split the u (split) dimension with
  // stride 16 (us = wave id); each lane owns 2 cells (C<=128, b64 L-loads)
  // or 4 cells (C>128, b128 L-loads). ftab is stored wave-permuted so each
  // wave reads its f-sequence as aligned float4 broadcasts. Operand
  // addresses are strength-reduced: off4[u+16]-off4[u] = 4000-16u exactly.
  __shared__ __align__(16) float E[EPAD];
  __shared__ __align__(16) float fp[NN];     // wave-permuted ftab
  __shared__ float Mar[NN];
  __shared__ unsigned RmaxU[NN];
  __shared__ int off4[NN + 1];
  __shared__ __align__(16) float Part[16 * PSTR];
  __shared__ float scratch[16];

  const int b = blockIdx.x >> 1;
  const int run = blockIdx.x & 1;
  const int tid = threadIdx.x;
  const int lane = tid & 63;
  const int q = tid >> 6;
  const bool isbyte = ((const u8*)mspan)[1] != 0;
  const size_t sbase = (size_t)b * (NN * NN);

  // sentence length
  int pred = 0;
  if (tid < NN) pred = mask_val(mspan, sbase + tid, isbyte) ? 1 : 0;
  const int len = __syncthreads_count(pred);

  if (tid <= NN) off4[tid] = 33280 - Fpad(NN - tid);
  for (int k = tid; k < EPAD; k += NTHREADS) E[k] = 0.f;
  for (int k = tid; k < 16 * PSTR; k += NTHREADS) Part[k] = 0.f;
  if (tid < NN) RmaxU[tid] = 0u;
  __syncthreads();

  // ---- diagonal 0 ----
  float a0 = -3.0e38f;
  if (tid < len) {
    size_t cell = sbase + (size_t)tid * NN + tid;
    a0 = score_val(slog[cell], sind, cell, run, isbyte);
  }
  float wm = a0;
  #pragma unroll
  for (int o = 1; o < 64; o <<= 1) wm = fmaxf(wm, __shfl_xor(wm, o, 64));
  if (lane == 0) scratch[q] = wm;
  __syncthreads();
  float M0 = scratch[0];
  #pragma unroll
  for (int k = 1; k < 16; ++k) M0 = fmaxf(M0, scratch[k]);
  if (tid < len) E[tid] = __expf(a0 - M0);
  if (tid == 0) { Mar[0] = M0; RmaxU[0] = __float_as_uint(1.0f); }
  double MarD = (double)M0;   // tid0's exact Mar chain
  __syncthreads();

  float myScore = 0.f;        // prefetched span score, carried across phases

  for (int w = 2; w <= len; ++w) {
    const int S = w - 1;
    const int Cw = len - w + 1;

    // ======== phase A: permuted ftab on waves 12..15 || finalize w-1 on 0..11
    if (tid >= 768) {
      const int u = tid - 768;
      float f = 0.f;
      if (u < S) {
        const int vd = S - 1 - u;
        double ex = (double)Mar[u] + (double)Mar[vd]
                  - (double)(Mar[w - 2] + Mar[0]);
        f = __expf((float)ex);
      }
      fp[((u & 15) << 4) + (u >> 4)] = f;
    } else if (w > 2) {
      const int Cp = Cw + 1;                  // cells of width w-1
      const int c = tid;
      float mx = 0.f;
      if (c < Cp) {
        float s = 0.f;
        #pragma unroll
        for (int k = 0; k < 16; ++k) s += Part[k * PSTR + c];
        const float corr = (Mar[w - 3] + Mar[0]) - Mar[w - 2];
        const float V = s * __expf(myScore + corr);
        E[off4[w - 2] + c] = V;
        mx = V;
      }
      #pragma unroll
      for (int o = 1; o < 64; o <<= 1) mx = fmaxf(mx, __shfl_xor(mx, o, 64));
      if (lane == 0 && mx > 0.f) atomicMax(&RmaxU[w - 2], __float_as_uint(mx));
    }
    __syncthreads();

    // ======== phase B: partial sums over u || Mar update || score prefetch
    {
      const int us = q;                          // wave id = split offset
      const int nj = (us < S) ? ((S - us + 15) >> 4) : 0;
      const int fbase = us << 4;

      if (Cw > 128) {
        // ---- V4: lane owns cells 4*lane .. 4*lane+3
        const int c0 = lane << 2;
        float s0 = 0.f, s1 = 0.f, s2 = 0.f, s3 = 0.f;
        if (nj > 0) {
          const int vd0 = S - 1 - us;
          int aL = off4[us] + c0;
          int aR = off4[vd0] + us + 1 + c0;
          int dL = 4000 - 16 * us;
          int dR = 16 * vd0 - 4240;
          #define ITER4(FV)                                                \
            { const float4 L = *(const float4*)&E[aL];                     \
              const float r0 = E[aR], r1 = E[aR+1], r2 = E[aR+2], r3 = E[aR+3]; \
              s0 = fmaf((FV) * L.x, r0, s0);                               \
              s1 = fmaf((FV) * L.y, r1, s1);                               \
              s2 = fmaf((FV) * L.z, r2, s2);                               \
              s3 = fmaf((FV) * L.w, r3, s3);                               \
              aL += dL; dL -= 256; aR += dR; dR -= 256; }
          const int nj4 = nj >> 2;
          for (int j4 = 0; j4 < nj4; ++j4) {
            const float4 ff = *(const float4*)&fp[fbase + (j4 << 2)];
            ITER4(ff.x) ITER4(ff.y) ITER4(ff.z) ITER4(ff.w)
          }
          for (int t = nj & ~3; t < nj; ++t) {
            const float f1 = fp[fbase + t];
            ITER4(f1)
          }
          #undef ITER4
        }
        *(float4*)&Part[q * PSTR + c0] = make_float4(s0, s1, s2, s3);
      } else {
        // ---- V2: lane owns cells 2*lane, 2*lane+1
        const int c0 = lane << 1;
        float s0 = 0.f, s1 = 0.f;
        if (nj > 0) {
          const int vd0 = S - 1 - us;
          int aL = off4[us] + c0;
          int aR = off4[vd0] + us + 1 + c0;
          int dL = 4000 - 16 * us;
          int dR = 16 * vd0 - 4240;
          #define ITER2(FV)                                                \
            { const float2 L = *(const float2*)&E[aL];                     \
              const float r0 = E[aR], r1 = E[aR+1];                        \
              s0 = fmaf((FV) * L.x, r0, s0);                               \
              s1 = fmaf((FV) * L.y, r1, s1);                               \
              aL += dL; dL -= 256; aR += dR; dR -= 256; }
          const int nj4 = nj >> 2;
          for (int j4 = 0; j4 < nj4; ++j4) {
            const float4 ff = *(const float4*)&fp[fbase + (j4 << 2)];
            ITER2(ff.x) ITER2(ff.y) ITER2(ff.z) ITER2(ff.w)
          }
          for (int t = nj & ~3; t < nj; ++t) {
            const float f1 = fp[fbase + t];
            ITER2(f1)
          }
          #undef ITER2
        }
        *(float2*)&Part[q * PSTR + c0] = make_float2(s0, s1);
      }

      // prefetch scores of diag d = w-1 for next phase A's finalize
      if (tid < Cw) {
        const size_t cell = sbase + (size_t)tid * NN + (tid + w - 1);
        myScore = score_val(slog[cell], sind, cell, run, isbyte);
      }
      if (tid == 0) {
        float lr = __logf(__uint_as_float(RmaxU[w - 2] | 1u));
        lr = fminf(fmaxf(lr, -40.f), 40.f);
        MarD += (double)lr;
        Mar[w - 1] = (float)MarD;
      }
    }
    __syncthreads();
  }

  // ---- finalize width == len (single cell c=0) ----
  if (tid == 0) {
    float ssum = 0.f;
    #pragma unroll
    for (int k = 0; k < 16; ++k) ssum += Part[k * PSTR];
    const float corr = (Mar[len - 2] + Mar[0]) - Mar[len - 1];
    double alpha = (double)Mar[len - 1] + (double)(myScore + corr)
                 + (double)__logf(ssum);
    wsv[run * BB + b] = (float)alpha;
    if (run == 0) wsv[2 * BB + b] = (float)len;
  }
}

extern "C" __global__ void loss_kernel(const float* __restrict__ wsv, float* __restrict__ out) {
  const int t = threadIdx.x;
  float diff = 0.0f, ln = 0.0f;
  if (t < BB) { diff = wsv[BB + t] - wsv[t]; ln = wsv[2 * BB + t]; }
  #pragma unroll
  for (int o = 1; o < 64; o <<= 1) {
    diff += __shfl_xor(diff, o, 64);
    ln += __shfl_xor(ln, o, 64);
  }
  if (t == 0) out[0] = diff / ln;
}

extern "C" void kernel_launch(void* const* d_in, const int* in_sizes, int n_in,
                              void* d_out, int out_size, void* d_ws, size_t ws_size,
                              hipStream_t stream) {
  const float2* slog = (const float2*)d_in[0];
  const void* sind = d_in[1];
  const void* mspan = d_in[2];
  float* wsv = (float*)d_ws;
  cyk_kernel<<<dim3(BB * 2), dim3(NTHREADS), 0, stream>>>(slog, sind, mspan, wsv);
  loss_kernel<<<dim3(1), dim3(64), 0, stream>>>(wsv, (float*)d_out);
}

// Round 6
// 665.930 us; speedup vs baseline: 1.0112x; 1.0112x over previous
//
#include <hip/hip_runtime.h>
#include <cstdint>
#include <cstddef>

#define NTH 1024
#define BB 16
#define NN 256
#define ELSZ 34560   // halves per chart arena (worst len=256: ~34312 used)
#define PARTSZ 4608  // halves

typedef unsigned char u8;
typedef unsigned short u16;
typedef unsigned int u32;

// Mask arrays may arrive as bool (1 byte), int32, or float32. Detect on
// device: maskspan[0,0,1] == 1 always (lens >= 128).
__device__ __forceinline__ bool mask_val(const void* p, size_t i, bool isb) {
  return isb ? (((const u8*)p)[i] != 0) : (((const int*)p)[i] != 0);
}
__device__ __forceinline__ float score_val(float2 v, const void* sind, size_t cell, int run, bool isb) {
  if (run == 0) return mask_val(sind, cell, isb) ? v.y : v.x;  // ob
  float m = fmaxf(v.x, v.y);                                   // allp
  return m + __logf(1.f + __expf(-fabsf(v.x - v.y)));
}
__device__ __forceinline__ u16 f2bf(float x) {  // RNE f32->bf16
  u32 u = __float_as_uint(x);
  return (u16)((u + 0x7fffu + ((u >> 16) & 1u)) >> 16);
}
__device__ __forceinline__ float bf2f(u16 h) { return __uint_as_float(((u32)h) << 16); }

// Inner u-loop: dual bf16 charts, both operands dense aligned ds_read_b64.
// P lane-groups each own one split u per iter (u = q + 16*(j*P+g)); each lane
// covers 4 cells c = 4r - (q&3). Addresses strength-reduced: over u-steps of
// h=16P the per-diagonal bases have constant 2nd difference -h^2 (the mod-4
// congruence pads are 4-periodic, h%4==0, so they cancel exactly).
template <int P>
__device__ __forceinline__ void inner_u(
    const u16* __restrict__ ELu, const u16* __restrict__ ERu, u16* __restrict__ PartU,
    const float* __restrict__ fp, const int* __restrict__ BLs, const int* __restrict__ BRs,
    int S, int q, int lane) {
  constexpr int NL = 64 / P;
  constexpr int h = 16 * P;
  constexpr int h2 = h * h;
  constexpr int RST = (P == 1) ? 260 : (P == 2) ? 132 : 68;
  const int s4 = q & 3;
  const int g = lane / NL;
  const int r = lane % NL;
  const int c0 = 4 * r - s4;
  const int nk = (q < S) ? ((S - q + 15) >> 4) : 0;
  const int nj = (nk + P - 1) / P;
  const int fb0 = __float_as_int(fp[q * 17 + (lane & 15)]);  // lane k holds f(u=q+16k)
  const int u0 = q + 16 * g;
  const int v0 = S - 1 - u0;
  const int v0c = v0 < 0 ? 0 : v0;
  const int vhc = (v0 - h) < 0 ? 0 : (v0 - h);
  int aL = BLs[u0] + c0;
  int dL = BLs[u0 + h] - BLs[u0];
  int aR = BRs[v0c] + u0 + 1 + c0;
  int dR = BRs[vhc] - BRs[v0c] + h;
  float s0 = 0.f, s1 = 0.f, s2 = 0.f, s3 = 0.f;
  #pragma unroll 4
  for (int j = 0; j < nj; ++j) {
    float f;
    if (P == 1) {
      f = __int_as_float(__builtin_amdgcn_readlane(fb0, j));
    } else if (P == 2) {
      const float fa = __int_as_float(__builtin_amdgcn_readlane(fb0, 2 * j));
      const float fb = __int_as_float(__builtin_amdgcn_readlane(fb0, 2 * j + 1));
      f = g ? fb : fa;
    } else {
      const float fa = __int_as_float(__builtin_amdgcn_readlane(fb0, 4 * j));
      const float fb = __int_as_float(__builtin_amdgcn_readlane(fb0, 4 * j + 1));
      const float fc = __int_as_float(__builtin_amdgcn_readlane(fb0, 4 * j + 2));
      const float fd = __int_as_float(__builtin_amdgcn_readlane(fb0, 4 * j + 3));
      f = (g & 2) ? ((g & 1) ? fd : fc) : ((g & 1) ? fb : fa);
    }
    const bool val = (j * P + g) < nk;   // dead groups: f==0 anyway; clamp addr
    const int aLr = val ? aL : 0;
    const int aRr = val ? aR : 0;
    const uint2 Lw = *(const uint2*)(ELu + aLr);
    const uint2 Rw = *(const uint2*)(ERu + aRr);
    const float l0 = __uint_as_float(Lw.x << 16);
    const float l1 = __uint_as_float(Lw.x & 0xffff0000u);
    const float l2 = __uint_as_float(Lw.y << 16);
    const float l3 = __uint_as_float(Lw.y & 0xffff0000u);
    const float r0 = __uint_as_float(Rw.x << 16);
    const float r1 = __uint_as_float(Rw.x & 0xffff0000u);
    const float r2 = __uint_as_float(Rw.y << 16);
    const float r3 = __uint_as_float(Rw.y & 0xffff0000u);
    s0 = fmaf(f * l0, r0, s0);
    s1 = fmaf(f * l1, r1, s1);
    s2 = fmaf(f * l2, r2, s2);
    s3 = fmaf(f * l3, r3, s3);
    aL += dL; dL -= h2;
    aR += dR; dR -= h2;
  }
  const int row = q * P + g;
  const u32 p0 = (u32)f2bf(s0) | ((u32)f2bf(s1) << 16);
  const u32 p1 = (u32)f2bf(s2) | ((u32)f2bf(s3) << 16);
  *(uint2*)(PartU + row * RST + (s4 + c0)) = make_uint2(p0, p1);  // = +4r, aligned
}

extern "C" __global__ void __launch_bounds__(NTH, 1)
cyk_kernel(const float2* __restrict__ slog, const void* __restrict__ sind,
           const void* __restrict__ mspan, float* __restrict__ wsv) {
  // alpha(d,c) = log(E[d][c]) + Mar[d]; Mar[d] = Mar[d-1] + clamp(log Rmax[d-1]).
  // EL: diag bases BL[d] == d (mod 4); ER: same contents, BR[d] == 3 (mod 4).
  __shared__ __align__(16) u16 ELu[ELSZ];
  __shared__ __align__(16) u16 ERu[ELSZ];
  __shared__ __align__(16) u16 PartU[PARTSZ];
  __shared__ float fp[272];      // wave-permuted split factors (stride 17)
  __shared__ float Mar[NN];
  __shared__ u32 RmaxU[NN];
  __shared__ int BLs[260];
  __shared__ int BRs[260];
  __shared__ float scr[16];

  const int b = blockIdx.x >> 1;
  const int run = blockIdx.x & 1;
  const int tid = threadIdx.x;
  const int lane = tid & 63;
  const int q = tid >> 6;
  const bool isb = ((const u8*)mspan)[1] != 0;
  const size_t sbase = (size_t)b * (NN * NN);

  int pred = 0;
  if (tid < NN) pred = mask_val(mspan, sbase + tid, isb) ? 1 : 0;
  const int len = __syncthreads_count(pred);

  // tid0 builds diag-base tables (gap in [4,7] keeps guards + congruence);
  // others zero both arenas (guards must be zero).
  if (tid == 0) {
    BLs[0] = 4; BRs[0] = 7;
    for (int d = 0; d < 259; ++d) {
      int sz = len - d; if (sz < 0) sz = 0;
      int nl_ = BLs[d] + sz;
      BLs[d + 1] = nl_ + 4 + ((((d + 1 - nl_) % 4) + 4) % 4);
      int nr_ = BRs[d] + sz;
      BRs[d + 1] = nr_ + 4 + ((((3 - nr_) % 4) + 4) % 4);
    }
  } else {
    for (int k = tid - 1; k < ELSZ / 2; k += NTH - 1) ((u32*)ELu)[k] = 0u;
    for (int k = tid - 1; k < ELSZ / 2; k += NTH - 1) ((u32*)ERu)[k] = 0u;
  }
  if (tid < NN) RmaxU[tid] = 0u;
  __syncthreads();

  // ---- diagonal 0 ----
  float a0 = -3.0e38f;
  if (tid < len) {
    size_t cell = sbase + (size_t)tid * NN + tid;
    a0 = score_val(slog[cell], sind, cell, run, isb);
  }
  float wm = a0;
  #pragma unroll
  for (int o = 1; o < 64; o <<= 1) wm = fmaxf(wm, __shfl_xor(wm, o, 64));
  if (lane == 0) scr[q] = wm;
  __syncthreads();
  float M0 = scr[0];
  #pragma unroll
  for (int k = 1; k < 16; ++k) M0 = fmaxf(M0, scr[k]);
  if (tid < len) {
    u16 e0 = f2bf(__expf(a0 - M0));
    ELu[BLs[0] + tid] = e0;
    ERu[BRs[0] + tid] = e0;
  }
  if (tid == 0) { Mar[0] = M0; RmaxU[0] = __float_as_uint(1.0f); }
  double MarD = (double)M0;
  __syncthreads();

  float myScore = 0.f;                       // prefetched span score (diag w-1)
  int prevRows = 1, prevRST = 260, prevLgP = 0;

  for (int w = 2; w <= len; ++w) {
    const int S = w - 1;
    const int C = len - w + 1;

    // ======== phase A: build fp(w) on waves 12..15 || finalize diag w-2
    if (tid >= 768) {
      if (w >= 4) {
        const int u = tid - 768;
        float fv = 0.f;
        if (u < S) {
          const int vd = S - 1 - u;
          double ex = (double)Mar[u] + (double)Mar[vd] - (double)Mar[w - 2] - (double)Mar[0];
          float exf = fminf((float)ex, 80.f);   // safety clamp: no Inf*0=NaN
          fv = __expf(exf);
        }
        fp[(u & 15) * 17 + (u >> 4)] = fv;
      }
    } else if (w >= 3) {
      const int c = tid;
      const int Cp = len - w + 2;              // cells of diag w-2
      float mx = 0.f;
      if (c < Cp) {
        float acc = 0.f;
        for (int k = 0; k < prevRows; ++k)
          acc += bf2f(PartU[k * prevRST + (((k >> prevLgP) & 3) + c)]);
        const float corr = (Mar[w - 3] + Mar[0]) - Mar[w - 2];
        const float V = acc * __expf(myScore + corr);
        const u16 vb = f2bf(V);
        ELu[BLs[w - 2] + c] = vb;
        ERu[BRs[w - 2] + c] = vb;
        mx = V;
      }
      #pragma unroll
      for (int o = 1; o < 64; o <<= 1) mx = fmaxf(mx, __shfl_xor(mx, o, 64));
      if (lane == 0 && mx > 0.f) atomicMax(&RmaxU[w - 2], __float_as_uint(mx));
    }
    __syncthreads();

    // ======== phase B: partial sums over u || Mar update || score prefetch
    if (w <= 3) {
      // specials (f == 1 exactly): thread per cell, scalar reads
      float sa = 0.f;
      if (tid < C) {
        if (w == 2) {
          sa = bf2f(ELu[BLs[0] + tid]) * bf2f(ELu[BLs[0] + tid + 1]);
        } else {
          sa = bf2f(ELu[BLs[0] + tid]) * bf2f(ELu[BLs[1] + tid + 1])
             + bf2f(ELu[BLs[1] + tid]) * bf2f(ELu[BLs[0] + tid + 2]);
        }
        PartU[tid] = f2bf(sa);
      }
      prevRows = 1; prevRST = 260; prevLgP = 0;
    } else {
      if (C + 3 > 128) {
        inner_u<1>(ELu, ERu, PartU, fp, BLs, BRs, S, q, lane);
        prevRows = 16; prevRST = 260; prevLgP = 0;
      } else if (C + 3 > 64) {
        inner_u<2>(ELu, ERu, PartU, fp, BLs, BRs, S, q, lane);
        prevRows = 32; prevRST = 132; prevLgP = 1;
      } else {
        inner_u<4>(ELu, ERu, PartU, fp, BLs, BRs, S, q, lane);
        prevRows = 64; prevRST = 68; prevLgP = 2;
      }
    }
    if (tid < C) {  // prefetch diag w-1 scores for next finalize
      const size_t cell = sbase + (size_t)tid * NN + (tid + w - 1);
      myScore = score_val(slog[cell], sind, cell, run, isb);
    }
    if (tid == 0) {
      float lr = __logf(__uint_as_float(RmaxU[w - 2] | 1u));
      lr = fminf(fmaxf(lr, -40.f), 40.f);
      MarD += (double)lr;
      Mar[w - 1] = (float)MarD;
    }
    __syncthreads();
  }

  // ---- finalize top cell (diag len-1, c = 0) ----
  if (tid == 0) {
    float ssum = 0.f;
    for (int k = 0; k < prevRows; ++k)
      ssum += bf2f(PartU[k * prevRST + ((k >> prevLgP) & 3)]);
    const float corr = (Mar[len - 2] + Mar[0]) - Mar[len - 1];
    double alpha = (double)Mar[len - 1] + (double)(myScore + corr) + (double)__logf(ssum);
    wsv[run * BB + b] = (float)alpha;
    if (run == 0) wsv[2 * BB + b] = (float)len;
  }
}

extern "C" __global__ void loss_kernel(const float* __restrict__ wsv, float* __restrict__ out) {
  const int t = threadIdx.x;
  float diff = 0.0f, ln = 0.0f;
  if (t < BB) { diff = wsv[BB + t] - wsv[t]; ln = wsv[2 * BB + t]; }
  #pragma unroll
  for (int o = 1; o < 64; o <<= 1) {
    diff += __shfl_xor(diff, o, 64);
    ln += __shfl_xor(ln, o, 64);
  }
  if (t == 0) out[0] = diff / ln;
}

extern "C" void kernel_launch(void* const* d_in, const int* in_sizes, int n_in,
                              void* d_out, int out_size, void* d_ws, size_t ws_size,
                              hipStream_t stream) {
  const float2* slog = (const float2*)d_in[0];
  const void* sind = d_in[1];
  const void* mspan = d_in[2];
  float* wsv = (float*)d_ws;
  cyk_kernel<<<dim3(BB * 2), dim3(NTH), 0, stream>>>(slog, sind, mspan, wsv);
  loss_kernel<<<dim3(1), dim3(64), 0, stream>>>(wsv, (float*)d_out);
}